// Round 15
// baseline (52.313 us; speedup 1.0000x reference)
//
#include <hip/hip_runtime.h>
#include <hip/hip_bf16.h>

#define B_  8
#define S_  2048
#define D_  128
#define H_  4
#define HD_ 32
#define BH_ (B_ * H_)

typedef __bf16 bf16x8 __attribute__((ext_vector_type(8)));
typedef float f32x16 __attribute__((ext_vector_type(16)));

__device__ inline bf16x8 ld8(const __hip_bfloat16* p) {
    return *reinterpret_cast<const bf16x8*>(p);
}
__device__ inline unsigned cvtpk(float lo, float hi) {
    unsigned r;
    asm("v_cvt_pk_bf16_f32 %0, %1, %2" : "=v"(r) : "v"(lo), "v"(hi));
    return r;
}
__device__ inline void swap32(unsigned &a, unsigned &b) {
    asm("v_permlane32_swap_b32 %0, %1" : "+v"(a), "+v"(b));
}
__device__ inline float ex2(float x) { return __builtin_amdgcn_exp2f(x); }

// ---------------------------------------------------------------------------
// Weight convert+transpose via LDS tiles (coalesced both sides).
// blocks 0..47: w_attn -> wt[384][128]; 48..63: w_proj -> wpt[128][128]
// ---------------------------------------------------------------------------
__global__ __launch_bounds__(256) void conv_w(const float* __restrict__ wa,
                                              const float* __restrict__ wp,
                                              __hip_bfloat16* __restrict__ wt,
                                              __hip_bfloat16* __restrict__ wpt) {
    __shared__ float tile[32][33];
    int bid = blockIdx.x;
    const float* src;
    __hip_bfloat16* dst;
    int N, k0, n0;
    if (bid < 48) { src = wa; dst = wt;  N = 384; k0 = (bid / 12) * 32; n0 = (bid % 12) * 32; }
    else { bid -= 48; src = wp; dst = wpt; N = 128; k0 = (bid / 4) * 32; n0 = (bid % 4) * 32; }
    const int r = threadIdx.x >> 5, c = threadIdx.x & 31;
#pragma unroll
    for (int j = 0; j < 4; ++j)
        tile[r + 8 * j][c] = src[(k0 + r + 8 * j) * N + n0 + c];
    __syncthreads();
#pragma unroll
    for (int j = 0; j < 4; ++j)
        dst[(n0 + r + 8 * j) * 128 + k0 + c] = __float2bfloat16(tile[c][r + 8 * j]);
}

// ---------------------------------------------------------------------------
// QKV GEMM, fused fp32->bf16 convert of x. Block = 4 waves (wave == head),
// m-tile = 32 rows. Q/K swapped operands -> vector stores; V -> Vt [HD][S].
// ---------------------------------------------------------------------------
__global__ __launch_bounds__(256) void qkv_mfma(const float* __restrict__ x,
                                                const __hip_bfloat16* __restrict__ wt,
                                                __hip_bfloat16* __restrict__ Qb,
                                                __hip_bfloat16* __restrict__ Kb,
                                                __hip_bfloat16* __restrict__ Vt) {
    const int mt   = blockIdx.x;                 // 0..511
    const int wave = threadIdx.x >> 6;           // head
    const int lane = threadIdx.x & 63;
    const int lq   = lane & 31;
    const int hi   = lane >> 5;
    const int m0   = mt * 32;

    const float* ax = x + (m0 + lq) * 128 + 8 * hi;
    const __hip_bfloat16* bq = wt + ((      wave * 32) + lq) * 128 + 8 * hi;
    const __hip_bfloat16* bk = wt + ((128 + wave * 32) + lq) * 128 + 8 * hi;
    const __hip_bfloat16* bv = wt + ((256 + wave * 32) + lq) * 128 + 8 * hi;

    f32x16 aq = {}, ak = {}, av = {};

    // depth-2 pipeline
    float4 x0a = *reinterpret_cast<const float4*>(ax);
    float4 x1a = *reinterpret_cast<const float4*>(ax + 4);
    bf16x8 bqa = ld8(bq), bka = ld8(bk), bva = ld8(bv);
    float4 x0b = *reinterpret_cast<const float4*>(ax + 16);
    float4 x1b = *reinterpret_cast<const float4*>(ax + 20);
    bf16x8 bqb = ld8(bq + 16), bkb = ld8(bk + 16), bvb = ld8(bv + 16);

#pragma unroll
    for (int ks = 0; ks < 8; ++ks) {
        const float4 cx0 = x0a, cx1 = x1a;
        const bf16x8 cbq = bqa, cbk = bka, cbv = bva;
        x0a = x0b; x1a = x1b; bqa = bqb; bka = bkb; bva = bvb;
        if (ks < 6) {
            x0b = *reinterpret_cast<const float4*>(ax + 16 * (ks + 2));
            x1b = *reinterpret_cast<const float4*>(ax + 16 * (ks + 2) + 4);
            bqb = ld8(bq + 16 * (ks + 2));
            bkb = ld8(bk + 16 * (ks + 2));
            bvb = ld8(bv + 16 * (ks + 2));
        }
        union { unsigned u[4]; bf16x8 v; } af;
        af.u[0] = cvtpk(cx0.x, cx0.y); af.u[1] = cvtpk(cx0.z, cx0.w);
        af.u[2] = cvtpk(cx1.x, cx1.y); af.u[3] = cvtpk(cx1.z, cx1.w);
        // swapped: D[n][m], lane = m-row  -> contiguous hd per thread
        aq = __builtin_amdgcn_mfma_f32_32x32x16_bf16(cbq, af.v, aq, 0, 0, 0);
        ak = __builtin_amdgcn_mfma_f32_32x32x16_bf16(cbk, af.v, ak, 0, 0, 0);
        // V: D[m][hd], lane = hd (for transposed store)
        av = __builtin_amdgcn_mfma_f32_32x32x16_bf16(af.v, cbv, av, 0, 0, 0);
    }

    const int b  = m0 >> 11;
    const int s0 = m0 & (S_ - 1);
    const int bh = b * H_ + wave;
    const float qs = 0.2550052557342824f;        // 1/sqrt(32) * log2(e)

    __hip_bfloat16* qrow = Qb + (bh * S_ + s0 + lq) * HD_ + 4 * hi;
    __hip_bfloat16* krow = Kb + (bh * S_ + s0 + lq) * HD_ + 4 * hi;
#pragma unroll
    for (int g = 0; g < 4; ++g) {
        union { __hip_bfloat16 h[4]; ushort4 u; } pq, pk;
#pragma unroll
        for (int j = 0; j < 4; ++j) {
            pq.h[j] = __float2bfloat16(aq[4 * g + j] * qs);
            pk.h[j] = __float2bfloat16(ak[4 * g + j]);
        }
        *reinterpret_cast<ushort4*>(qrow + 8 * g) = pq.u;
        *reinterpret_cast<ushort4*>(krow + 8 * g) = pk.u;
    }
    __hip_bfloat16* vbase = Vt + (bh * HD_ + lq) * S_ + s0;
#pragma unroll
    for (int g = 0; g < 4; ++g) {
        union { __hip_bfloat16 h[4]; ushort4 u; } pv;
#pragma unroll
        for (int j = 0; j < 4; ++j) pv.h[j] = __float2bfloat16(av[4 * g + j]);
        *reinterpret_cast<ushort4*>(vbase + 8 * g + 4 * hi) = pv.u;
    }
}

// ---------------------------------------------------------------------------
// Flash attention, 128-q blocks: each block owns 128 q-rows (sub-tiles 0..3),
// so every loaded K/V tile feeds up to FOUR 32x32 score tiles -> K/V traffic
// ~70 MB (was 266 at 32q, 135 at 64q). 4-way k-split, 1-deep prefetch,
// zero-offset softmax. 512 blocks (2/CU), longest chunks first.
// ---------------------------------------------------------------------------
__global__ __launch_bounds__(256, 2) void fattn_kernel(
    const __hip_bfloat16* __restrict__ Qb,
    const __hip_bfloat16* __restrict__ Kb,
    const __hip_bfloat16* __restrict__ Vt,
    __hip_bfloat16* __restrict__ AOb)
{
    __shared__ float Ol[4][128][33];
    __shared__ float Ll[4][128];

    const int bh   = blockIdx.x & 31;             // head -> stable XCD
    const int ch   = 15 - (blockIdx.x >> 5);      // chunk 0..15, longest first
    const int tid  = threadIdx.x;
    const int wv   = tid >> 6;
    const int lane = tid & 63;
    const int lq   = lane & 31;
    const int hi   = lane >> 5;

    const int q0 = ch * 128;
    const int dt = 4 * ch;                        // diagonal tile of sub-tile 0
    const int nt = dt + 4;

    const __hip_bfloat16* qrow0 = Qb + (bh * S_ + q0 + lq) * HD_ + 8 * hi;
    const bf16x8 qf0a = ld8(qrow0),            qf0b = ld8(qrow0 + 16);
    const bf16x8 qf1a = ld8(qrow0 + 32 * HD_), qf1b = ld8(qrow0 + 32 * HD_ + 16);
    const bf16x8 qf2a = ld8(qrow0 + 64 * HD_), qf2b = ld8(qrow0 + 64 * HD_ + 16);
    const bf16x8 qf3a = ld8(qrow0 + 96 * HD_), qf3b = ld8(qrow0 + 96 * HD_ + 16);

    const __hip_bfloat16* kp = Kb + bh * S_ * HD_ + lq * HD_ + 8 * hi;
    const __hip_bfloat16* vp = Vt + (bh * HD_ + lq) * S_ + 8 * hi;

    f32x16 oacc0 = {}, oacc1 = {}, oacc2 = {}, oacc3 = {};
    float ls0 = 0.f, ls1 = 0.f, ls2 = 0.f, ls3 = 0.f;

    // 1-deep prefetch
    bf16x8 k0a = {}, k1a = {}, v0a = {}, v1a = {};
    if (wv < nt) {
        k0a = ld8(kp + wv * 32 * HD_); k1a = ld8(kp + wv * 32 * HD_ + 16);
        v0a = ld8(vp + wv * 32);       v1a = ld8(vp + wv * 32 + 16);
    }

    for (int t = wv; t < nt; t += 4) {
        const bf16x8 ck0 = k0a, ck1 = k1a, cv0 = v0a, cv1 = v1a;
        if (t + 4 < nt) {
            const __hip_bfloat16* kn = kp + (t + 4) * 32 * HD_;
            const __hip_bfloat16* vn = vp + (t + 4) * 32;
            k0a = ld8(kn); k1a = ld8(kn + 16);
            v0a = ld8(vn); v1a = ld8(vn + 16);
        }

#define SUBTILE(I, QA, QB, OACC, LS)                                            \
        if (t <= dt + I) {                                                      \
            __builtin_amdgcn_s_setprio(1);                                      \
            f32x16 s = {};                                                      \
            s = __builtin_amdgcn_mfma_f32_32x32x16_bf16(ck0, QA, s, 0, 0, 0);   \
            s = __builtin_amdgcn_mfma_f32_32x32x16_bf16(ck1, QB, s, 0, 0, 0);   \
            __builtin_amdgcn_s_setprio(0);                                      \
            if (t == dt + I) {                                                  \
                _Pragma("unroll")                                               \
                for (int r = 0; r < 16; ++r) {                                  \
                    const int kloc = (r & 3) + 8 * (r >> 2) + 4 * hi;           \
                    s[r] = (kloc > lq) ? -1e30f : s[r];                         \
                }                                                               \
            }                                                                   \
            _Pragma("unroll")                                                   \
            for (int r = 0; r < 16; ++r) s[r] = ex2(s[r]);                      \
            {                                                                   \
                float p0 = (s[0] + s[1]) + (s[2] + s[3]);                       \
                float p1 = (s[4] + s[5]) + (s[6] + s[7]);                       \
                float p2 = (s[8] + s[9]) + (s[10] + s[11]);                     \
                float p3 = (s[12] + s[13]) + (s[14] + s[15]);                   \
                LS += (p0 + p1) + (p2 + p3);                                    \
            }                                                                   \
            unsigned a0 = cvtpk(s[0], s[1]),   a1 = cvtpk(s[2], s[3]);          \
            unsigned a2 = cvtpk(s[4], s[5]),   a3 = cvtpk(s[6], s[7]);          \
            swap32(a0, a2); swap32(a1, a3);                                     \
            unsigned b0 = cvtpk(s[8], s[9]),   b1 = cvtpk(s[10], s[11]);        \
            unsigned b2 = cvtpk(s[12], s[13]), b3 = cvtpk(s[14], s[15]);        \
            swap32(b0, b2); swap32(b1, b3);                                     \
            union { unsigned u[4]; bf16x8 v; } pb0, pb1;                        \
            pb0.u[0] = a0; pb0.u[1] = a1; pb0.u[2] = a2; pb0.u[3] = a3;         \
            pb1.u[0] = b0; pb1.u[1] = b1; pb1.u[2] = b2; pb1.u[3] = b3;         \
            __builtin_amdgcn_s_setprio(1);                                      \
            OACC = __builtin_amdgcn_mfma_f32_32x32x16_bf16(cv0, pb0.v, OACC, 0, 0, 0); \
            OACC = __builtin_amdgcn_mfma_f32_32x32x16_bf16(cv1, pb1.v, OACC, 0, 0, 0); \
            __builtin_amdgcn_s_setprio(0);                                      \
        }

        SUBTILE(0, qf0a, qf0b, oacc0, ls0)
        SUBTILE(1, qf1a, qf1b, oacc1, ls1)
        SUBTILE(2, qf2a, qf2b, oacc2, ls2)
        SUBTILE(3, qf3a, qf3b, oacc3, ls3)
#undef SUBTILE
    }

    ls0 += __shfl_xor(ls0, 32);
    ls1 += __shfl_xor(ls1, 32);
    ls2 += __shfl_xor(ls2, 32);
    ls3 += __shfl_xor(ls3, 32);

#pragma unroll
    for (int r = 0; r < 16; ++r) {
        const int d = (r & 3) + 8 * (r >> 2) + 4 * hi;
        Ol[wv][lq][d]      = oacc0[r];
        Ol[wv][32 + lq][d] = oacc1[r];
        Ol[wv][64 + lq][d] = oacc2[r];
        Ol[wv][96 + lq][d] = oacc3[r];
    }
    if (hi == 0) {
        Ll[wv][lq]      = ls0;
        Ll[wv][32 + lq] = ls1;
        Ll[wv][64 + lq] = ls2;
        Ll[wv][96 + lq] = ls3;
    }
    __syncthreads();

    // combine 4 partials: thread -> (q = tid>>1, 16 d's)
    const int q  = tid >> 1;                      // 0..127
    const int d0 = (tid & 1) * 16;                // 0 or 16
    const float lst = Ll[0][q] + Ll[1][q] + Ll[2][q] + Ll[3][q];
    const float inv = 1.f / lst;

    const int b = bh >> 2, h = bh & 3;
    __hip_bfloat16* orow = AOb + (b * S_ + q0 + q) * D_ + h * HD_ + d0;
#pragma unroll
    for (int g = 0; g < 4; ++g) {
        union { __hip_bfloat16 h4[4]; ushort4 u; } st;
#pragma unroll
        for (int j = 0; j < 4; ++j) {
            const int d = d0 + 4 * g + j;
            const float o = Ol[0][q][d] + Ol[1][q][d] + Ol[2][q][d] + Ol[3][q][d];
            st.h4[j] = __float2bfloat16(o * inv);
        }
        *reinterpret_cast<ushort4*>(orow + 4 * g) = st.u;
    }
}

// ---------------------------------------------------------------------------
// Projection GEMM: [16384,128]x[128,128] -> fp32. Swapped operands: lane =
// out row -> 4x float4 stores. All fragment loads hoisted.
// ---------------------------------------------------------------------------
__global__ __launch_bounds__(256) void proj_mfma(const __hip_bfloat16* __restrict__ AOb,
                                                 const __hip_bfloat16* __restrict__ wpt,
                                                 float* __restrict__ out) {
    const int m0   = blockIdx.x * 32;
    const int wave = threadIdx.x >> 6;
    const int lane = threadIdx.x & 63;
    const int lq   = lane & 31;
    const int hi   = lane >> 5;
    const int n0   = wave * 32;

    const __hip_bfloat16* ap = AOb + (m0 + lq) * 128 + 8 * hi;
    const __hip_bfloat16* bp = wpt + (n0 + lq) * 128 + 8 * hi;

    bf16x8 A[8], Bf[8];
#pragma unroll
    for (int ks = 0; ks < 8; ++ks) {
        A[ks]  = ld8(ap + 16 * ks);
        Bf[ks] = ld8(bp + 16 * ks);
    }

    f32x16 acc = {};
#pragma unroll
    for (int ks = 0; ks < 8; ++ks)   // swapped: D[n][m], lane = m-row
        acc = __builtin_amdgcn_mfma_f32_32x32x16_bf16(Bf[ks], A[ks], acc, 0, 0, 0);

    float* orow = out + (m0 + lq) * 128 + n0 + 4 * hi;
#pragma unroll
    for (int g = 0; g < 4; ++g) {
        float4 st = make_float4(acc[4 * g], acc[4 * g + 1], acc[4 * g + 2], acc[4 * g + 3]);
        *reinterpret_cast<float4*>(orow + 8 * g) = st;
    }
}

// ---------------------------------------------------------------------------
extern "C" void kernel_launch(void* const* d_in, const int* in_sizes, int n_in,
                              void* d_out, int out_size, void* d_ws, size_t ws_size,
                              hipStream_t stream) {
    const float* x      = (const float*)d_in[0];
    const float* w_attn = (const float*)d_in[1];
    const float* w_proj = (const float*)d_in[2];
    float* out = (float*)d_out;

    char* ws = (char*)d_ws;
    __hip_bfloat16* Qb  = (__hip_bfloat16*)(ws);                     // 4 MB
    __hip_bfloat16* Kb  = (__hip_bfloat16*)(ws + (4  << 20));        // 4 MB
    __hip_bfloat16* Vt  = (__hip_bfloat16*)(ws + (8  << 20));        // 4 MB
    __hip_bfloat16* AOb = (__hip_bfloat16*)(ws + (12 << 20));        // 4 MB
    __hip_bfloat16* wt  = (__hip_bfloat16*)(ws + (16 << 20));        // 96 KB
    __hip_bfloat16* wpt = (__hip_bfloat16*)(ws + (16 << 20) + (128 << 10)); // 32 KB

    conv_w<<<64, 256, 0, stream>>>(w_attn, w_proj, wt, wpt);
    qkv_mfma<<<512, 256, 0, stream>>>(x, wt, Qb, Kb, Vt);
    fattn_kernel<<<BH_ * 16, 256, 0, stream>>>(Qb, Kb, Vt, AOb);
    proj_mfma<<<512, 256, 0, stream>>>(AOb, wpt, out);
}

// Round 16
// 47.076 us; speedup vs baseline: 1.1112x; 1.1112x over previous
//
#include <hip/hip_runtime.h>
#include <hip/hip_bf16.h>

#define B_  8
#define S_  2048
#define D_  128
#define H_  4
#define HD_ 32
#define BH_ (B_ * H_)

typedef __bf16 bf16x8 __attribute__((ext_vector_type(8)));
typedef float f32x16 __attribute__((ext_vector_type(16)));

__device__ inline bf16x8 ld8(const __hip_bfloat16* p) {
    return *reinterpret_cast<const bf16x8*>(p);
}
__device__ inline unsigned cvtpk(float lo, float hi) {
    unsigned r;
    asm("v_cvt_pk_bf16_f32 %0, %1, %2" : "=v"(r) : "v"(lo), "v"(hi));
    return r;
}
__device__ inline void swap32(unsigned &a, unsigned &b) {
    asm("v_permlane32_swap_b32 %0, %1" : "+v"(a), "+v"(b));
}
__device__ inline float ex2(float x) { return __builtin_amdgcn_exp2f(x); }

// ---------------------------------------------------------------------------
// QKV GEMM with in-block weight staging (replaces conv_w).
// Block = (mblk, head): 128 m-rows x one head's 96 w-rows (Q,K,V slices).
// Stage wa slice -> LDS bf16 [96][136] (transposed, padded, 16B-aligned rows),
// then the r14-validated MFMA loop with B-fragments read from LDS.
// ---------------------------------------------------------------------------
__global__ __launch_bounds__(256) void qkv_mfma(const float* __restrict__ x,
                                                const float* __restrict__ wa,
                                                __hip_bfloat16* __restrict__ Qb,
                                                __hip_bfloat16* __restrict__ Kb,
                                                __hip_bfloat16* __restrict__ Vt) {
    __shared__ __align__(16) __hip_bfloat16 wl[96][136];

    const int head = blockIdx.x & 3;
    const int mblk = blockIdx.x >> 2;
    const int tid  = threadIdx.x;

    // stage: wl[sec*32+nloc][k] = wa[k][sec*128 + head*32 + nloc]
    for (int idx = tid; idx < 128 * 96; idx += 256) {
        const int k = idx / 96;
        const int c = idx - k * 96;               // c = sec*32 + nloc
        const int sec = c >> 5, nloc = c & 31;
        wl[c][k] = __float2bfloat16(wa[k * 384 + sec * 128 + head * 32 + nloc]);
    }
    __syncthreads();

    const int wave = tid >> 6;                    // m-subtile
    const int lane = tid & 63;
    const int lq   = lane & 31;
    const int hi   = lane >> 5;
    const int m0   = mblk * 128 + wave * 32;

    const float* ax = x + (m0 + lq) * 128 + 8 * hi;
    const __hip_bfloat16* bq = &wl[lq][8 * hi];
    const __hip_bfloat16* bk = &wl[32 + lq][8 * hi];
    const __hip_bfloat16* bv = &wl[64 + lq][8 * hi];

    f32x16 aq = {}, ak = {}, av = {};
#pragma unroll
    for (int ks = 0; ks < 8; ++ks) {
        float4 x0 = *reinterpret_cast<const float4*>(ax + 16 * ks);
        float4 x1 = *reinterpret_cast<const float4*>(ax + 16 * ks + 4);
        union { unsigned u[4]; bf16x8 v; } af;
        af.u[0] = cvtpk(x0.x, x0.y); af.u[1] = cvtpk(x0.z, x0.w);
        af.u[2] = cvtpk(x1.x, x1.y); af.u[3] = cvtpk(x1.z, x1.w);
        const bf16x8 wqf = ld8(bq + 16 * ks);
        const bf16x8 wkf = ld8(bk + 16 * ks);
        const bf16x8 wvf = ld8(bv + 16 * ks);
        // Q/K swapped (lane = m-row) -> contiguous hd per thread on store
        aq = __builtin_amdgcn_mfma_f32_32x32x16_bf16(wqf, af.v, aq, 0, 0, 0);
        ak = __builtin_amdgcn_mfma_f32_32x32x16_bf16(wkf, af.v, ak, 0, 0, 0);
        // V normal (lane = hd) for transposed Vt store
        av = __builtin_amdgcn_mfma_f32_32x32x16_bf16(af.v, wvf, av, 0, 0, 0);
    }

    const int b  = m0 >> 11;
    const int s0 = m0 & (S_ - 1);
    const int bh = b * H_ + head;
    const float qs = 0.2550052557342824f;         // 1/sqrt(32) * log2(e)

    __hip_bfloat16* qrow = Qb + (bh * S_ + s0 + lq) * HD_ + 4 * hi;
    __hip_bfloat16* krow = Kb + (bh * S_ + s0 + lq) * HD_ + 4 * hi;
#pragma unroll
    for (int g = 0; g < 4; ++g) {
        union { __hip_bfloat16 h[4]; ushort4 u; } pq, pk;
#pragma unroll
        for (int j = 0; j < 4; ++j) {
            pq.h[j] = __float2bfloat16(aq[4 * g + j] * qs);
            pk.h[j] = __float2bfloat16(ak[4 * g + j]);
        }
        *reinterpret_cast<ushort4*>(qrow + 8 * g) = pq.u;
        *reinterpret_cast<ushort4*>(krow + 8 * g) = pk.u;
    }
    __hip_bfloat16* vbase = Vt + (bh * HD_ + lq) * S_ + s0;
#pragma unroll
    for (int g = 0; g < 4; ++g) {
        union { __hip_bfloat16 h[4]; ushort4 u; } pv;
#pragma unroll
        for (int j = 0; j < 4; ++j) pv.h[j] = __float2bfloat16(av[4 * g + j]);
        *reinterpret_cast<ushort4*>(vbase + 8 * g + 4 * hi) = pv.u;
    }
}

// ---------------------------------------------------------------------------
// Flash attention, 64-q blocks (r14 validated): each block owns 64 q-rows
// (halves A and B) sharing every loaded K/V tile. 4-way k-split, 1-deep
// prefetch, zero-offset softmax. 1024 blocks, longest-first.
// ---------------------------------------------------------------------------
__global__ __launch_bounds__(256, 4) void fattn_kernel(
    const __hip_bfloat16* __restrict__ Qb,
    const __hip_bfloat16* __restrict__ Kb,
    const __hip_bfloat16* __restrict__ Vt,
    __hip_bfloat16* __restrict__ AOb)
{
    __shared__ float Ol[4][64][33];
    __shared__ float Ll[4][64];

    const int bh   = blockIdx.x & 31;             // head -> stable XCD
    const int qt2  = 31 - (blockIdx.x >> 5);      // 0..31, longest first
    const int tid  = threadIdx.x;
    const int wv   = tid >> 6;
    const int lane = tid & 63;
    const int lq   = lane & 31;
    const int hi   = lane >> 5;

    const int q0  = qt2 * 64;
    const int qtA = 2 * qt2;
    const int qtB = qtA + 1;
    const int nt  = qtB + 1;

    const __hip_bfloat16* qrowA = Qb + (bh * S_ + q0 + lq) * HD_ + 8 * hi;
    const __hip_bfloat16* qrowB = qrowA + 32 * HD_;
    const bf16x8 qfA0 = ld8(qrowA), qfA1 = ld8(qrowA + 16);
    const bf16x8 qfB0 = ld8(qrowB), qfB1 = ld8(qrowB + 16);

    const __hip_bfloat16* kp = Kb + bh * S_ * HD_ + lq * HD_ + 8 * hi;
    const __hip_bfloat16* vp = Vt + (bh * HD_ + lq) * S_ + 8 * hi;

    f32x16 oaccA = {}, oaccB = {};
    float lsumA = 0.f, lsumB = 0.f;

    bf16x8 k0a = {}, k1a = {}, v0a = {}, v1a = {};
    if (wv < nt) {
        k0a = ld8(kp + wv * 32 * HD_); k1a = ld8(kp + wv * 32 * HD_ + 16);
        v0a = ld8(vp + wv * 32);       v1a = ld8(vp + wv * 32 + 16);
    }

    for (int t = wv; t < nt; t += 4) {
        const bf16x8 ck0 = k0a, ck1 = k1a, cv0 = v0a, cv1 = v1a;
        if (t + 4 < nt) {
            const __hip_bfloat16* kn = kp + (t + 4) * 32 * HD_;
            const __hip_bfloat16* vn = vp + (t + 4) * 32;
            k0a = ld8(kn); k1a = ld8(kn + 16);
            v0a = ld8(vn); v1a = ld8(vn + 16);
        }

        if (t <= qtA) {
            __builtin_amdgcn_s_setprio(1);
            f32x16 s = {};
            s = __builtin_amdgcn_mfma_f32_32x32x16_bf16(ck0, qfA0, s, 0, 0, 0);
            s = __builtin_amdgcn_mfma_f32_32x32x16_bf16(ck1, qfA1, s, 0, 0, 0);
            __builtin_amdgcn_s_setprio(0);

            if (t == qtA) {
#pragma unroll
                for (int r = 0; r < 16; ++r) {
                    const int kloc = (r & 3) + 8 * (r >> 2) + 4 * hi;
                    s[r] = (kloc > lq) ? -1e30f : s[r];
                }
            }
#pragma unroll
            for (int r = 0; r < 16; ++r) s[r] = ex2(s[r]);
            {
                float p0 = (s[0] + s[1]) + (s[2] + s[3]);
                float p1 = (s[4] + s[5]) + (s[6] + s[7]);
                float p2 = (s[8] + s[9]) + (s[10] + s[11]);
                float p3 = (s[12] + s[13]) + (s[14] + s[15]);
                lsumA += (p0 + p1) + (p2 + p3);
            }
            unsigned a0 = cvtpk(s[0], s[1]),   a1 = cvtpk(s[2], s[3]);
            unsigned a2 = cvtpk(s[4], s[5]),   a3 = cvtpk(s[6], s[7]);
            swap32(a0, a2); swap32(a1, a3);
            unsigned b0 = cvtpk(s[8], s[9]),   b1 = cvtpk(s[10], s[11]);
            unsigned b2 = cvtpk(s[12], s[13]), b3 = cvtpk(s[14], s[15]);
            swap32(b0, b2); swap32(b1, b3);
            union { unsigned u[4]; bf16x8 v; } pb0, pb1;
            pb0.u[0] = a0; pb0.u[1] = a1; pb0.u[2] = a2; pb0.u[3] = a3;
            pb1.u[0] = b0; pb1.u[1] = b1; pb1.u[2] = b2; pb1.u[3] = b3;

            __builtin_amdgcn_s_setprio(1);
            oaccA = __builtin_amdgcn_mfma_f32_32x32x16_bf16(cv0, pb0.v, oaccA, 0, 0, 0);
            oaccA = __builtin_amdgcn_mfma_f32_32x32x16_bf16(cv1, pb1.v, oaccA, 0, 0, 0);
            __builtin_amdgcn_s_setprio(0);
        }

        {
            __builtin_amdgcn_s_setprio(1);
            f32x16 s = {};
            s = __builtin_amdgcn_mfma_f32_32x32x16_bf16(ck0, qfB0, s, 0, 0, 0);
            s = __builtin_amdgcn_mfma_f32_32x32x16_bf16(ck1, qfB1, s, 0, 0, 0);
            __builtin_amdgcn_s_setprio(0);

            if (t == qtB) {
#pragma unroll
                for (int r = 0; r < 16; ++r) {
                    const int kloc = (r & 3) + 8 * (r >> 2) + 4 * hi;
                    s[r] = (kloc > lq) ? -1e30f : s[r];
                }
            }
#pragma unroll
            for (int r = 0; r < 16; ++r) s[r] = ex2(s[r]);
            {
                float p0 = (s[0] + s[1]) + (s[2] + s[3]);
                float p1 = (s[4] + s[5]) + (s[6] + s[7]);
                float p2 = (s[8] + s[9]) + (s[10] + s[11]);
                float p3 = (s[12] + s[13]) + (s[14] + s[15]);
                lsumB += (p0 + p1) + (p2 + p3);
            }
            unsigned a0 = cvtpk(s[0], s[1]),   a1 = cvtpk(s[2], s[3]);
            unsigned a2 = cvtpk(s[4], s[5]),   a3 = cvtpk(s[6], s[7]);
            swap32(a0, a2); swap32(a1, a3);
            unsigned b0 = cvtpk(s[8], s[9]),   b1 = cvtpk(s[10], s[11]);
            unsigned b2 = cvtpk(s[12], s[13]), b3 = cvtpk(s[14], s[15]);
            swap32(b0, b2); swap32(b1, b3);
            union { unsigned u[4]; bf16x8 v; } pb0, pb1;
            pb0.u[0] = a0; pb0.u[1] = a1; pb0.u[2] = a2; pb0.u[3] = a3;
            pb1.u[0] = b0; pb1.u[1] = b1; pb1.u[2] = b2; pb1.u[3] = b3;

            __builtin_amdgcn_s_setprio(1);
            oaccB = __builtin_amdgcn_mfma_f32_32x32x16_bf16(cv0, pb0.v, oaccB, 0, 0, 0);
            oaccB = __builtin_amdgcn_mfma_f32_32x32x16_bf16(cv1, pb1.v, oaccB, 0, 0, 0);
            __builtin_amdgcn_s_setprio(0);
        }
    }

    lsumA += __shfl_xor(lsumA, 32);
    lsumB += __shfl_xor(lsumB, 32);

#pragma unroll
    for (int r = 0; r < 16; ++r) {
        const int d = (r & 3) + 8 * (r >> 2) + 4 * hi;
        Ol[wv][lq][d]      = oaccA[r];
        Ol[wv][32 + lq][d] = oaccB[r];
    }
    if (hi == 0) { Ll[wv][lq] = lsumA; Ll[wv][32 + lq] = lsumB; }
    __syncthreads();

    const int q  = tid >> 2;                      // 0..63
    const int d0 = (tid & 3) * 8;                 // 0,8,16,24
    const float lst = Ll[0][q] + Ll[1][q] + Ll[2][q] + Ll[3][q];
    const float inv = 1.f / lst;

    const int b = bh >> 2, h = bh & 3;
    __hip_bfloat16* orow = AOb + (b * S_ + q0 + q) * D_ + h * HD_ + d0;
#pragma unroll
    for (int g = 0; g < 2; ++g) {
        union { __hip_bfloat16 h4[4]; ushort4 u; } st;
#pragma unroll
        for (int j = 0; j < 4; ++j) {
            const int d = d0 + 4 * g + j;
            const float o = Ol[0][q][d] + Ol[1][q][d] + Ol[2][q][d] + Ol[3][q][d];
            st.h4[j] = __float2bfloat16(o * inv);
        }
        *reinterpret_cast<ushort4*>(orow + 4 * g) = st.u;
    }
}

// ---------------------------------------------------------------------------
// Projection GEMM with in-block weight staging (full w_proj -> LDS bf16).
// [16384,128]x[128,128] -> fp32. Swapped operands -> 4x float4 stores.
// ---------------------------------------------------------------------------
__global__ __launch_bounds__(256) void proj_mfma(const __hip_bfloat16* __restrict__ AOb,
                                                 const float* __restrict__ wp,
                                                 float* __restrict__ out) {
    __shared__ __align__(16) __hip_bfloat16 wl[128][136];

    const int tid = threadIdx.x;
    // stage: wl[n][k] = wp[k][n]
    for (int idx = tid; idx < 128 * 128; idx += 256) {
        const int k = idx >> 7, n = idx & 127;
        wl[n][k] = __float2bfloat16(wp[idx]);
    }
    __syncthreads();

    const int m0   = blockIdx.x * 32;
    const int wave = tid >> 6;
    const int lane = tid & 63;
    const int lq   = lane & 31;
    const int hi   = lane >> 5;
    const int n0   = wave * 32;

    const __hip_bfloat16* ap = AOb + (m0 + lq) * 128 + 8 * hi;
    const __hip_bfloat16* bp = &wl[n0 + lq][8 * hi];

    f32x16 acc = {};
#pragma unroll
    for (int ks = 0; ks < 8; ++ks) {
        const bf16x8 af = ld8(ap + 16 * ks);
        const bf16x8 bf = ld8(bp + 16 * ks);
        // swapped: D[n][m], lane = m-row
        acc = __builtin_amdgcn_mfma_f32_32x32x16_bf16(bf, af, acc, 0, 0, 0);
    }

    float* orow = out + (m0 + lq) * 128 + n0 + 4 * hi;
#pragma unroll
    for (int g = 0; g < 4; ++g) {
        float4 st = make_float4(acc[4 * g], acc[4 * g + 1], acc[4 * g + 2], acc[4 * g + 3]);
        *reinterpret_cast<float4*>(orow + 8 * g) = st;
    }
}

// ---------------------------------------------------------------------------
extern "C" void kernel_launch(void* const* d_in, const int* in_sizes, int n_in,
                              void* d_out, int out_size, void* d_ws, size_t ws_size,
                              hipStream_t stream) {
    const float* x      = (const float*)d_in[0];
    const float* w_attn = (const float*)d_in[1];
    const float* w_proj = (const float*)d_in[2];
    float* out = (float*)d_out;

    char* ws = (char*)d_ws;
    __hip_bfloat16* Qb  = (__hip_bfloat16*)(ws);                     // 4 MB
    __hip_bfloat16* Kb  = (__hip_bfloat16*)(ws + (4  << 20));        // 4 MB
    __hip_bfloat16* Vt  = (__hip_bfloat16*)(ws + (8  << 20));        // 4 MB
    __hip_bfloat16* AOb = (__hip_bfloat16*)(ws + (12 << 20));        // 4 MB

    qkv_mfma<<<512, 256, 0, stream>>>(x, w_attn, Qb, Kb, Vt);
    fattn_kernel<<<BH_ * 32, 256, 0, stream>>>(Qb, Kb, Vt, AOb);
    proj_mfma<<<512, 256, 0, stream>>>(AOb, w_proj, out);
}